// Round 3
// baseline (65.829 us; speedup 1.0000x reference)
//
#include <hip/hip_runtime.h>
#include <utility>

#define BATCH 32768
#define NPHI 35
#define SWEEPS 6

// ---------- compile-time combinatorics ----------
constexpr int choose2(int n){ return (n*(n-1))/2; }

constexpr int tri_id_sorted(int a,int b,int c){
  int id=0;
  for(int x=0;x<a;++x) id += choose2(6-x);
  for(int y=a+1;y<b;++y) id += (6-y);
  id += (c-b-1);
  return id;
}

constexpr int tri_id3(int a,int b,int c){
  int x=a,y=b,z=c;
  if (x>y){int t=x;x=y;y=t;}
  if (y>z){int t=y;y=z;z=t;}
  if (x>y){int t=x;x=y;y=t;}
  return tri_id_sorted(x,y,z);
}

constexpr int sgn3(int a,int b,int c){
  int inv = (a>b)+(a>c)+(b>c);
  return (inv&1)? -1 : 1;
}

constexpr int UT(int i,int j){
  return i*7 - (i*(i-1))/2 + (j-i);
}

constexpr int pair_k(int g){
  int idx=0;
  for(int k=0;k<7;++k) for(int l=k+1;l<7;++l){ if(idx==g) return k; ++idx; }
  return 0;
}
constexpr int pair_l(int g){
  int idx=0;
  for(int k=0;k<7;++k) for(int l=k+1;l<7;++l){ if(idx==g) return l; ++idx; }
  return 0;
}

// ---------- per-(k,l)-group straight-line program ----------
// T phase: T[j] (+)= s * ph[comp] * ph[tri(j,m,n)]   (50 ops/group)
// B phase: U[UT(i,j)] += s * ph[tri(i,k,l)] * T[j]   (<=25 ops/group)
struct GProg {
  int nt, nb;
  signed char t_dst[50], t_a[50], t_b[50], t_s[50]; unsigned char t_init[50];
  signed char b_dst[26], b_a[26], b_b[26], b_s[26];
};

constexpr GProg build_group(int k,int l){
  GProg P{}; P.nt=0; P.nb=0;
  bool tinit[7]={};
  for(int m=0;m<7;++m) for(int n2=m+1;n2<7;++n2){
    if(m==k||m==l||n2==k||n2==l) continue;
    int comp[3]={0,0,0}; int cn=0;
    for(int x=0;x<7;++x) if(x!=k&&x!=l&&x!=m&&x!=n2){ comp[cn]=x; ++cn; }
    int perm[7]={k,l,m,n2,comp[0],comp[1],comp[2]};
    int invc=0;
    for(int i=0;i<7;++i) for(int j=i+1;j<7;++j) if(perm[i]>perm[j]) ++invc;
    const int es=(invc&1)? -1 : 1;
    const int tcomp=tri_id_sorted(comp[0],comp[1],comp[2]);
    for(int j=0;j<7;++j){
      if(j==m||j==n2) continue;
      P.t_dst[P.nt]=(signed char)j;
      P.t_a [P.nt]=(signed char)tcomp;
      P.t_b [P.nt]=(signed char)tri_id3(j,m,n2);
      P.t_s [P.nt]=(signed char)(es*sgn3(j,m,n2));
      P.t_init[P.nt]=tinit[j]?0:1; tinit[j]=true;
      ++P.nt;
    }
  }
  for(int i=0;i<7;++i){
    if(i==k||i==l) continue;
    for(int j=i;j<7;++j){
      P.b_dst[P.nb]=(signed char)UT(i,j);
      P.b_a [P.nb]=(signed char)tri_id3(i,k,l);
      P.b_b [P.nb]=(signed char)j;
      P.b_s [P.nb]=(signed char)sgn3(i,k,l);
      ++P.nb;
    }
  }
  return P;
}

template<int G> inline constexpr GProg GP = build_group(pair_k(G), pair_l(G));

// ---------- guaranteed-constant-index execution ----------
template<int G,int Q>
__device__ __forceinline__ void t_step(float (&T)[7], const float (&ph)[NPHI]){
  constexpr int d=GP<G>.t_dst[Q], a=GP<G>.t_a[Q], b=GP<G>.t_b[Q];
  constexpr bool neg=(GP<G>.t_s[Q]<0), ini=(GP<G>.t_init[Q]!=0);
  const float x = neg ? -ph[a] : ph[a];
  if constexpr (ini) T[d] = x*ph[b];
  else               T[d] = fmaf(x, ph[b], T[d]);
}

template<int G,int Q>
__device__ __forceinline__ void b_step(float (&U)[28], const float (&T)[7],
                                       const float (&ph)[NPHI]){
  constexpr int d=GP<G>.b_dst[Q], a=GP<G>.b_a[Q], b=GP<G>.b_b[Q];
  constexpr bool neg=(GP<G>.b_s[Q]<0);
  const float x = neg ? -ph[a] : ph[a];
  U[d] = fmaf(x, T[b], U[d]);
}

template<int G,int... TQ>
__device__ __forceinline__ void run_t(float (&T)[7], const float (&ph)[NPHI],
                                      std::integer_sequence<int,TQ...>){
  (t_step<G,TQ>(T,ph), ...);
}
template<int G,int... BQ>
__device__ __forceinline__ void run_b(float (&U)[28], const float (&T)[7],
                                      const float (&ph)[NPHI],
                                      std::integer_sequence<int,BQ...>){
  (b_step<G,BQ>(U,T,ph), ...);
}

template<int G>
__device__ __forceinline__ void do_group(float (&U)[28], const float (&ph)[NPHI]){
  float T[7];
  run_t<G>(T, ph, std::make_integer_sequence<int, GP<G>.nt>{});
  run_b<G>(U, T, ph, std::make_integer_sequence<int, GP<G>.nb>{});
  // Hard scheduling fence: caps live set at ~80 VGPRs, makes spill impossible.
  __builtin_amdgcn_sched_barrier(0);
}

template<int... G>
__device__ __forceinline__ void all_groups(float (&U)[28], const float (&ph)[NPHI],
                                           std::integer_sequence<int,G...>){
  (do_group<G>(U,ph), ...);
}

// ---------- kernel ----------
__global__ __launch_bounds__(64,1)
void PositivityConstraint_89086211654295_kernel(const float* __restrict__ phi,
                                                float* __restrict__ out){
  const int gid = blockIdx.x*64 + threadIdx.x;   // BATCH == 512*64 exactly

  const float* __restrict__ p = phi + (size_t)gid * NPHI;
  float ph[NPHI];
  #pragma unroll
  for (int i=0;i<NPHI;++i) ph[i] = p[i];

  float U[28];
  #pragma unroll
  for (int i=0;i<28;++i) U[i]=0.f;

  all_groups(U, ph, std::make_integer_sequence<int,21>{});

  float A[28];
  #pragma unroll
  for (int i=0;i<28;++i) A[i] = U[i]*(1.0f/6.0f);

  // cyclic Jacobi, SWEEPS sweeps, constant indices, single-rcp rotation:
  //   tau = (aqq-app)/(2apq);  t = sgn(tau)/(|tau|+sqrt(1+tau^2))
  //       = sgn(h) * s2 / (|h| + sqrt(h^2 + s2^2)),  s2=2apq, h=aqq-app
  for (int sweep=0; sweep<SWEEPS; ++sweep){
    #pragma unroll
    for (int p1=0;p1<7;++p1){
      #pragma unroll
      for (int q1=p1+1;q1<7;++q1){
        const float apq = A[UT(p1,q1)];
        const float app = A[UT(p1,p1)];
        const float aqq = A[UT(q1,q1)];
        const float s2  = apq + apq;
        const float h   = aqq - app;
        const float w   = fmaf(s2, s2, h*h);
        const float r   = __builtin_amdgcn_sqrtf(w);
        const float den = fabsf(h) + r + 1e-38f;   // >0 always; apq==0 -> t==0
        const float rc  = __builtin_amdgcn_rcpf(den);
        float t = s2 * rc;
        t = (h < 0.0f) ? -t : t;
        const float c = __builtin_amdgcn_rsqf(fmaf(t,t,1.0f));
        const float s = t*c;
        A[UT(p1,p1)] = fmaf(-t, apq, app);
        A[UT(q1,q1)] = fmaf( t, apq, aqq);
        A[UT(p1,q1)] = 0.0f;
        #pragma unroll
        for (int r2=0;r2<7;++r2){
          if (r2==p1 || r2==q1) continue;
          const int irp = (r2<p1)? UT(r2,p1) : UT(p1,r2);
          const int irq = (r2<q1)? UT(r2,q1) : UT(q1,r2);
          const float arp = A[irp], arq = A[irq];
          A[irp] = fmaf(c, arp, -(s*arq));
          A[irq] = fmaf(c, arq,  (s*arp));
        }
      }
    }
  }

  // det(B) = prod eig; eig(g) = eig(B) / (|det B|+1e-12)^(1/9)
  float det = 1.0f;
  #pragma unroll
  for (int i=0;i<7;++i) det *= A[UT(i,i)];
  const float ad = fabsf(det) + 1e-12f;
  const float scale = __builtin_amdgcn_exp2f(__builtin_amdgcn_logf(ad) * (1.0f/9.0f));
  const float inv = __builtin_amdgcn_rcpf(scale);

  float sum = 0.0f;
  #pragma unroll
  for (int i=0;i<7;++i){
    const float ev = A[UT(i,i)]*inv;
    sum += fmaxf(1e-6f - ev, 0.0f);
  }
  out[gid] = sum;
}

// ---------- launch ----------
extern "C" void kernel_launch(void* const* d_in, const int* in_sizes, int n_in,
                              void* d_out, int out_size, void* d_ws, size_t ws_size,
                              hipStream_t stream) {
  const float* phi = (const float*)d_in[0];
  float* out = (float*)d_out;
  (void)in_sizes; (void)n_in; (void)out_size; (void)d_ws; (void)ws_size;
  hipLaunchKernelGGL(PositivityConstraint_89086211654295_kernel,
                     dim3(BATCH/64), dim3(64), 0, stream, phi, out);
}